// Round 5
// baseline (31603.781 us; speedup 1.0000x reference)
//
#include <hip/hip_runtime.h>
#include <hip/hip_bf16.h>

// LSTM (1 layer): B=64, S=512, I=H=1024. Output = final cell state c [1,64,1024] fp32.
// fp32-accurate GEMMs via bf16 split-2 (3-product) MFMA.
//   x_proj: m97-style 128x128-tile GEMM with global_load_lds + XCD-chunked swizzle.
//   recurrence: persistent kernel, grid barrier per step. h exchanged via
//   device-coherent (agent-scope relaxed atomic) loads/stores -> NO cache-wide
//   acquire-invalidate at the barrier; w_hh/xp stay L1/L2-resident across steps.

#define B_ 64
#define S_ 512
#define I_ 1024
#define H_ 1024
#define G_ 4096  // 4*H
#define NBLK 64  // persistent grid

typedef __attribute__((ext_vector_type(8))) short bf16x8;
typedef __attribute__((ext_vector_type(4))) float f32x4;

__device__ __forceinline__ unsigned short f2bf(float f) {
  unsigned u = __float_as_uint(f);
  u += 0x7FFFu + ((u >> 16) & 1u);
  return (unsigned short)(u >> 16);
}
__device__ __forceinline__ float bf2f(unsigned short b) {
  return __uint_as_float(((unsigned)b) << 16);
}
__device__ __forceinline__ void gld16(const void* g, void* l) {
  __builtin_amdgcn_global_load_lds((const __attribute__((address_space(1))) void*)g,
                                   (__attribute__((address_space(3))) void*)l, 16, 0, 0);
}
__device__ __forceinline__ f32x4 mfma16(bf16x8 a, bf16x8 b, f32x4 c) {
  return __builtin_amdgcn_mfma_f32_16x16x32_bf16(a, b, c, 0, 0, 0);
}
// 16B device-coherent load (2x relaxed agent-scope u64 atomics -> read-through at
// the coherence point; no stale data, no cache-wide invalidation needed)
__device__ __forceinline__ bf16x8 ldh16(const unsigned long long* p) {
  union { unsigned long long q[2]; bf16x8 v; } u;
  u.q[0] = __hip_atomic_load((unsigned long long*)p, __ATOMIC_RELAXED, __HIP_MEMORY_SCOPE_AGENT);
  u.q[1] = __hip_atomic_load((unsigned long long*)p + 1, __ATOMIC_RELAXED, __HIP_MEMORY_SCOPE_AGENT);
  return u.v;
}

// ---------------- split fp32 matrix -> bf16 hi/lo planes ----------------
__global__ void split_mat(const float* __restrict__ src, unsigned short* __restrict__ hi,
                          unsigned short* __restrict__ lo, int n4) {
  int idx = blockIdx.x * 256 + threadIdx.x;
  if (idx >= n4) return;
  float4 v = ((const float4*)src)[idx];
  ushort4 h, l;
  h.x = f2bf(v.x); l.x = f2bf(v.x - bf2f(h.x));
  h.y = f2bf(v.y); l.y = f2bf(v.y - bf2f(h.y));
  h.z = f2bf(v.z); l.z = f2bf(v.z - bf2f(h.z));
  h.w = f2bf(v.w); l.w = f2bf(v.w - bf2f(h.w));
  ((ushort4*)hi)[idx] = h;
  ((ushort4*)lo)[idx] = l;
}

// ---------------- bias = b_ih + b_hh ; h/c init ; barrier counter init ----------------
__global__ void prep(const float* __restrict__ h0, const float* __restrict__ c0,
                     const float* __restrict__ b_ih, const float* __restrict__ b_hh,
                     unsigned short* __restrict__ hhi0, unsigned short* __restrict__ hlo0,
                     float* __restrict__ c, float* __restrict__ bias,
                     unsigned* __restrict__ cnt) {
  int idx = blockIdx.x * 256 + threadIdx.x;
  if (idx == 0) *cnt = 0u;
  if (idx < G_) bias[idx] = b_ih[idx] + b_hh[idx];
  if (idx < B_ * H_) {
    int k = idx & (H_ - 1);
    float v = h0[k];
    unsigned short hh = f2bf(v);
    hhi0[idx] = hh;
    hlo0[idx] = f2bf(v - bf2f(hh));
    c[idx] = c0[k];
  }
}

// ---------------- split x chunk into A-matrix layout [m=(t_local*64+b)][i] ----------------
__global__ void split_x(const float* __restrict__ x, unsigned short* __restrict__ xhi,
                        unsigned short* __restrict__ xlo, int t0) {
  int idx = blockIdx.x * 256 + threadIdx.x;
  int i4 = (idx & 255) * 4;
  int m = idx >> 8;
  int b = m & 63, tl = m >> 6;
  float4 v = *(const float4*)(x + ((size_t)b * S_ + (size_t)(t0 + tl)) * I_ + i4);
  ushort4 h, l;
  h.x = f2bf(v.x); l.x = f2bf(v.x - bf2f(h.x));
  h.y = f2bf(v.y); l.y = f2bf(v.y - bf2f(h.y));
  h.z = f2bf(v.z); l.z = f2bf(v.z - bf2f(h.z));
  h.w = f2bf(v.w); l.w = f2bf(v.w - bf2f(h.w));
  *(ushort4*)(xhi + (size_t)m * I_ + i4) = h;
  *(ushort4*)(xlo + (size_t)m * I_ + i4) = l;
}

// ---------------- x_proj GEMM: [Tc*64 x 1024] * [1024 x 4096]^T (+bias) ----------------
// 1-D grid with XCD-chunked, bx-major swizzle: each XCD owns a contiguous strip of
// N-panels so its B working set (~2MB) stays L2-resident.
__global__ __launch_bounds__(256) void xproj_gemm(
    const unsigned short* __restrict__ xhi, const unsigned short* __restrict__ xlo,
    const unsigned short* __restrict__ whi, const unsigned short* __restrict__ wlo,
    const float* __restrict__ bias, float* __restrict__ xp, int mblk) {
  __shared__ unsigned short Ah[128 * 32], Al[128 * 32], Bh[128 * 32], Bl[128 * 32];
  const int tid = threadIdx.x, lane = tid & 63, wv = tid >> 6;
  const int l15 = lane & 15, kg = lane >> 4;
  const int wm = wv >> 1, wn = wv & 1;
  // swizzle: nwg = 32*mblk (always %8==0); XCD k gets wg in [k*nwg/8, (k+1)*nwg/8)
  const int nwg = gridDim.x;
  const int wg = (blockIdx.x & 7) * (nwg >> 3) + (blockIdx.x >> 3);
  const int bx = wg / mblk, by = wg % mblk;
  const size_t aRow0 = (size_t)by * 128, bRow0 = (size_t)bx * 128;

  f32x4 acc[4][4];
#pragma unroll
  for (int a = 0; a < 4; ++a)
#pragma unroll
    for (int b2 = 0; b2 < 4; ++b2)
#pragma unroll
      for (int e = 0; e < 4; ++e) acc[a][b2][e] = 0.f;

  const int r0 = wv * 2;
  const int rowIn = lane >> 2;
  const int kb = (lane & 3) * 16;

  for (int kt = 0; kt < 32; ++kt) {
#pragma unroll
    for (int j = 0; j < 2; ++j) {
      const int ld = (r0 + j) * 1024;
      const int row = (r0 + j) * 16 + rowIn;
      const size_t ka = (size_t)kt * 64 + kb;
      gld16((const char*)xhi + (aRow0 + row) * 2048 + ka, (char*)Ah + ld);
      gld16((const char*)xlo + (aRow0 + row) * 2048 + ka, (char*)Al + ld);
      gld16((const char*)whi + (bRow0 + row) * 2048 + ka, (char*)Bh + ld);
      gld16((const char*)wlo + (bRow0 + row) * 2048 + ka, (char*)Bl + ld);
    }
    __syncthreads();
    bf16x8 ah[4], al[4], bh[4], bl[4];
#pragma unroll
    for (int f = 0; f < 4; ++f) {
      ah[f] = *(const bf16x8*)&Ah[(wm * 64 + f * 16 + l15) * 32 + kg * 8];
      al[f] = *(const bf16x8*)&Al[(wm * 64 + f * 16 + l15) * 32 + kg * 8];
      bh[f] = *(const bf16x8*)&Bh[(wn * 64 + f * 16 + l15) * 32 + kg * 8];
      bl[f] = *(const bf16x8*)&Bl[(wn * 64 + f * 16 + l15) * 32 + kg * 8];
    }
#pragma unroll
    for (int mf = 0; mf < 4; ++mf)
#pragma unroll
      for (int nf = 0; nf < 4; ++nf) {
        acc[mf][nf] = mfma16(ah[mf], bh[nf], acc[mf][nf]);
        acc[mf][nf] = mfma16(al[mf], bh[nf], acc[mf][nf]);
        acc[mf][nf] = mfma16(ah[mf], bl[nf], acc[mf][nf]);
      }
    __syncthreads();
  }
#pragma unroll
  for (int nf = 0; nf < 4; ++nf) {
    const int col = (int)bRow0 + wn * 64 + nf * 16 + l15;
    const float bv = bias[col];
#pragma unroll
    for (int mf = 0; mf < 4; ++mf)
#pragma unroll
      for (int i = 0; i < 4; ++i) {
        const size_t m = aRow0 + (size_t)(wm * 64 + mf * 16 + kg * 4 + i);
        xp[m * G_ + col] = acc[mf][nf][i] + bv;
      }
  }
}

// ---------------- persistent recurrence: Tc steps, grid barrier per step ----------------
// 64 blocks x 1024 thr (16 waves = 4 gates x 4 K-slices). Block nt owns H-cols
// nt*16..+16 (all 4 gates, all 64 batches). c register-resident. h exchanged
// coherently (agent atomics); w_hh planes stay cached (hi in VGPRs, lo in L2).
__global__ __launch_bounds__(1024) void lstm_persist(
    const float* __restrict__ xp_c,
    unsigned short* __restrict__ h_hi0, unsigned short* __restrict__ h_lo0,
    unsigned short* __restrict__ h_hi1, unsigned short* __restrict__ h_lo1,
    float* __restrict__ c,
    const unsigned short* __restrict__ whi, const unsigned short* __restrict__ wlo,
    float* __restrict__ out, unsigned* __restrict__ cnt, int t0, int Tc) {
  __shared__ float gl[16 * 64 * 16];  // [kh*4+g][batch][j] : 64 KB
  const int tid = threadIdx.x, lane = tid & 63, wv = tid >> 6;
  const int g = wv & 3, kh = wv >> 2;
  const int l15 = lane & 15, kg = lane >> 4;
  const int nt = blockIdx.x;

  // w_hh fragments: hi plane register-resident, lo plane streamed (stays L2-hot)
  const int wrow = g * 1024 + nt * 16 + l15;
  const unsigned short* bp_h = whi + (size_t)wrow * H_ + kh * 256 + kg * 8;
  const unsigned short* bp_l = wlo + (size_t)wrow * H_ + kh * 256 + kg * 8;
  bf16x8 bh_r[8];
#pragma unroll
  for (int kt = 0; kt < 8; ++kt) bh_r[kt] = *(const bf16x8*)(bp_h + kt * 32);

  const int eb = tid >> 4, ej = tid & 15;
  const int col = nt * 16 + ej;
  const int ci = eb * H_ + col;
  float creg = c[ci];

  const int aoff = kh * 256 + kg * 8;  // elements; 16B-aligned

  for (int tl = 0; tl < Tc; ++tl) {
    const int t = t0 + tl;
    const unsigned long long* hi_in =
        (const unsigned long long*)((t & 1) ? h_hi1 : h_hi0);
    const unsigned long long* lo_in =
        (const unsigned long long*)((t & 1) ? h_lo1 : h_lo0);
    unsigned short* hi_out = (t & 1) ? h_hi0 : h_hi1;
    unsigned short* lo_out = (t & 1) ? h_lo0 : h_lo1;

    // issue xp loads early; consumed after the MFMA phase (normal cached loads)
    const float* xpr = xp_c + ((size_t)tl * B_ + eb) * G_;
    float xq0 = xpr[col], xq1 = xpr[col + 1024], xq2 = xpr[col + 2048], xq3 = xpr[col + 3072];

    f32x4 acc[4];
#pragma unroll
    for (int m = 0; m < 4; ++m)
#pragma unroll
      for (int e = 0; e < 4; ++e) acc[m][e] = 0.f;

    const unsigned long long* ap_h = hi_in + ((size_t)l15 * H_ + aoff) / 4;
    const unsigned long long* ap_l = lo_in + ((size_t)l15 * H_ + aoff) / 4;
#pragma unroll
    for (int kt = 0; kt < 8; ++kt) {
      const bf16x8 bl = *(const bf16x8*)(bp_l + kt * 32);
#pragma unroll
      for (int mf = 0; mf < 4; ++mf) {
        const bf16x8 ah = ldh16(ap_h + ((size_t)mf * 16 * H_ + (size_t)kt * 32) / 4);
        const bf16x8 al = ldh16(ap_l + ((size_t)mf * 16 * H_ + (size_t)kt * 32) / 4);
        acc[mf] = mfma16(ah, bh_r[kt], acc[mf]);
        acc[mf] = mfma16(al, bh_r[kt], acc[mf]);
        acc[mf] = mfma16(ah, bl, acc[mf]);
      }
    }
#pragma unroll
    for (int mf = 0; mf < 4; ++mf)
#pragma unroll
      for (int i = 0; i < 4; ++i)
        gl[(wv * 64 + mf * 16 + kg * 4 + i) * 16 + l15] = acc[mf][i];
    __syncthreads();

    float xs[4];
#pragma unroll
    for (int gg = 0; gg < 4; ++gg) {
      float s = 0.f;
#pragma unroll
      for (int k2 = 0; k2 < 4; ++k2) s += gl[((k2 * 4 + gg) * 64 + eb) * 16 + ej];
      xs[gg] = s;
    }
    const float xi = xs[0] + xq0;
    const float xf = xs[1] + xq1;
    const float xg = xs[2] + xq2;
    const float xo = xs[3] + xq3;
    const float ig = 1.f / (1.f + __expf(-xi));
    const float fg = 1.f / (1.f + __expf(-xf));
    const float gt = tanhf(xg);
    const float og = 1.f / (1.f + __expf(-xo));
    creg = fg * creg + ig * gt;
    const float hn = og * tanhf(creg);
    const unsigned short hh = f2bf(hn);
    const unsigned short hl = f2bf(hn - bf2f(hh));
    // device-coherent h publish (write-through; no dirty L2 lines to flush)
    __hip_atomic_store(hi_out + ci, hh, __ATOMIC_RELAXED, __HIP_MEMORY_SCOPE_AGENT);
    __hip_atomic_store(lo_out + ci, hl, __ATOMIC_RELAXED, __HIP_MEMORY_SCOPE_AGENT);
    if (t == S_ - 1) out[ci] = creg;

    // ---- grid barrier: release arrival, relaxed spin, NO acquire-invalidate ----
    __syncthreads();  // all threads' h stores drained (vmcnt 0) before arrival
    if (tid == 0) {
      __hip_atomic_fetch_add(cnt, 1u, __ATOMIC_RELEASE, __HIP_MEMORY_SCOPE_AGENT);
      const unsigned tgt = (unsigned)(t + 1) * (unsigned)NBLK;
      while (__hip_atomic_load(cnt, __ATOMIC_RELAXED, __HIP_MEMORY_SCOPE_AGENT) < tgt) {
      }
      __atomic_signal_fence(__ATOMIC_ACQUIRE);  // compiler-only; h reads are coherent
    }
    __syncthreads();
  }
  c[ci] = creg;
}

extern "C" void kernel_launch(void* const* d_in, const int* in_sizes, int n_in,
                              void* d_out, int out_size, void* d_ws, size_t ws_size,
                              hipStream_t stream) {
  const float* x = (const float*)d_in[0];
  const float* h0 = (const float*)d_in[1];
  const float* c0 = (const float*)d_in[2];
  const float* w_ih = (const float*)d_in[3];
  const float* w_hh = (const float*)d_in[4];
  const float* b_ih = (const float*)d_in[5];
  const float* b_hh = (const float*)d_in[6];
  float* out = (float*)d_out;

  char* p = (char*)d_ws;
  auto carve = [&](size_t bytes) {
    char* r = p;
    p += (bytes + 255) & ~(size_t)255;
    return r;
  };
  const size_t wBytes = (size_t)G_ * H_ * 2;  // 8 MB per plane
  unsigned short* wih_hi = (unsigned short*)carve(wBytes);
  unsigned short* wih_lo = (unsigned short*)carve(wBytes);
  unsigned short* whh_hi = (unsigned short*)carve(wBytes);
  unsigned short* whh_lo = (unsigned short*)carve(wBytes);
  float* bias = (float*)carve((size_t)G_ * 4);
  unsigned short* hhi0 = (unsigned short*)carve((size_t)B_ * H_ * 2);
  unsigned short* hhi1 = (unsigned short*)carve((size_t)B_ * H_ * 2);
  unsigned short* hlo0 = (unsigned short*)carve((size_t)B_ * H_ * 2);
  unsigned short* hlo1 = (unsigned short*)carve((size_t)B_ * H_ * 2);
  float* cbuf = (float*)carve((size_t)B_ * H_ * 4);
  unsigned* cnt = (unsigned*)carve(256);
  const size_t fixed = (size_t)(p - (char*)d_ws);

  const size_t per_t = (size_t)B_ * I_ * 2 * 2 + (size_t)B_ * G_ * 4 + 1024;
  long long Tl = 2;
  if (ws_size > fixed) Tl = (long long)((ws_size - fixed) / per_t);
  int T = (int)(Tl > S_ ? S_ : Tl);
  T &= ~1;
  if (T < 2) T = 2;
  unsigned short* xhi = (unsigned short*)carve((size_t)T * B_ * I_ * 2);
  unsigned short* xlo = (unsigned short*)carve((size_t)T * B_ * I_ * 2);
  float* xp = (float*)carve((size_t)T * B_ * G_ * 4);

  split_mat<<<(G_ * H_ / 4 + 255) / 256, 256, 0, stream>>>(w_ih, wih_hi, wih_lo, G_ * H_ / 4);
  split_mat<<<(G_ * H_ / 4 + 255) / 256, 256, 0, stream>>>(w_hh, whh_hi, whh_lo, G_ * H_ / 4);
  prep<<<(B_ * H_ + 255) / 256, 256, 0, stream>>>(h0, c0, b_ih, b_hh, hhi0, hlo0, cbuf, bias,
                                                  cnt);

  int t0 = 0;
  while (t0 < S_) {
    const int Tc = (S_ - t0 < T) ? (S_ - t0) : T;
    const int mblk = Tc * B_ / 128;
    split_x<<<Tc * B_ * I_ / 4 / 256, 256, 0, stream>>>(x, xhi, xlo, t0);
    xproj_gemm<<<32 * mblk, 256, 0, stream>>>(xhi, xlo, wih_hi, wih_lo, bias, xp, mblk);
    lstm_persist<<<NBLK, 1024, 0, stream>>>(xp, hhi0, hlo0, hhi1, hlo1, cbuf, whh_hi, whh_lo,
                                            out, cnt, t0, Tc);
    t0 += Tc;
  }
}

// Round 11
// 9457.086 us; speedup vs baseline: 3.3418x; 3.3418x over previous
//
#include <hip/hip_runtime.h>
#include <hip/hip_bf16.h>

// LSTM (1 layer): B=64, S=512, I=H=1024. Output = final cell state c [1,64,1024] fp32.
// fp32-accurate GEMMs via bf16 split-2 (3-product) MFMA.
//   x_proj: m97-style 128x128-tile GEMM with global_load_lds (2D grid).
//   recurrence: persistent kernel, grid barrier per step (bounded spin as a
//   container-safety net). h exchanged via device-coherent relaxed agent atomics,
//   BULK-staged into LDS (quarter-K double-buffer, issue-early/write-late) so
//   MFMA reads are local ds_read_b128.

#define B_ 64
#define S_ 512
#define I_ 1024
#define H_ 1024
#define G_ 4096  // 4*H
#define NBLK 64  // persistent grid

typedef __attribute__((ext_vector_type(8))) short bf16x8;
typedef __attribute__((ext_vector_type(4))) float f32x4;
typedef unsigned long long u64;

__device__ __forceinline__ unsigned short f2bf(float f) {
  unsigned u = __float_as_uint(f);
  u += 0x7FFFu + ((u >> 16) & 1u);
  return (unsigned short)(u >> 16);
}
__device__ __forceinline__ float bf2f(unsigned short b) {
  return __uint_as_float(((unsigned)b) << 16);
}
__device__ __forceinline__ void gld16(const void* g, void* l) {
  __builtin_amdgcn_global_load_lds((const __attribute__((address_space(1))) void*)g,
                                   (__attribute__((address_space(3))) void*)l, 16, 0, 0);
}
__device__ __forceinline__ f32x4 mfma16(bf16x8 a, bf16x8 b, f32x4 c) {
  return __builtin_amdgcn_mfma_f32_16x16x32_bf16(a, b, c, 0, 0, 0);
}
__device__ __forceinline__ u64 ldc8(const void* p) {  // coherent 8B load (L2-bypass)
  return __hip_atomic_load((const u64*)p, __ATOMIC_RELAXED, __HIP_MEMORY_SCOPE_AGENT);
}

// ---------------- split fp32 matrix -> bf16 hi/lo planes ----------------
__global__ void split_mat(const float* __restrict__ src, unsigned short* __restrict__ hi,
                          unsigned short* __restrict__ lo, int n4) {
  int idx = blockIdx.x * 256 + threadIdx.x;
  if (idx >= n4) return;
  float4 v = ((const float4*)src)[idx];
  ushort4 h, l;
  h.x = f2bf(v.x); l.x = f2bf(v.x - bf2f(h.x));
  h.y = f2bf(v.y); l.y = f2bf(v.y - bf2f(h.y));
  h.z = f2bf(v.z); l.z = f2bf(v.z - bf2f(h.z));
  h.w = f2bf(v.w); l.w = f2bf(v.w - bf2f(h.w));
  ((ushort4*)hi)[idx] = h;
  ((ushort4*)lo)[idx] = l;
}

// ---------------- bias = b_ih + b_hh ; h/c init ; barrier counter init ----------------
__global__ void prep(const float* __restrict__ h0, const float* __restrict__ c0,
                     const float* __restrict__ b_ih, const float* __restrict__ b_hh,
                     unsigned short* __restrict__ hhi0, unsigned short* __restrict__ hlo0,
                     float* __restrict__ c, float* __restrict__ bias,
                     unsigned* __restrict__ cnt) {
  int idx = blockIdx.x * 256 + threadIdx.x;
  if (idx == 0) *cnt = 0u;
  if (idx < G_) bias[idx] = b_ih[idx] + b_hh[idx];
  if (idx < B_ * H_) {
    int k = idx & (H_ - 1);
    float v = h0[k];
    unsigned short hh = f2bf(v);
    hhi0[idx] = hh;
    hlo0[idx] = f2bf(v - bf2f(hh));
    c[idx] = c0[k];
  }
}

// ---------------- split x chunk into A-matrix layout [m=(t_local*64+b)][i] ----------------
__global__ void split_x(const float* __restrict__ x, unsigned short* __restrict__ xhi,
                        unsigned short* __restrict__ xlo, int t0) {
  int idx = blockIdx.x * 256 + threadIdx.x;
  int i4 = (idx & 255) * 4;
  int m = idx >> 8;
  int b = m & 63, tl = m >> 6;
  float4 v = *(const float4*)(x + ((size_t)b * S_ + (size_t)(t0 + tl)) * I_ + i4);
  ushort4 h, l;
  h.x = f2bf(v.x); l.x = f2bf(v.x - bf2f(h.x));
  h.y = f2bf(v.y); l.y = f2bf(v.y - bf2f(h.y));
  h.z = f2bf(v.z); l.z = f2bf(v.z - bf2f(h.z));
  h.w = f2bf(v.w); l.w = f2bf(v.w - bf2f(h.w));
  *(ushort4*)(xhi + (size_t)m * I_ + i4) = h;
  *(ushort4*)(xlo + (size_t)m * I_ + i4) = l;
}

// ---------------- x_proj GEMM: [Tc*64 x 1024] * [1024 x 4096]^T (+bias) ----------------
__global__ __launch_bounds__(256) void xproj_gemm(
    const unsigned short* __restrict__ xhi, const unsigned short* __restrict__ xlo,
    const unsigned short* __restrict__ whi, const unsigned short* __restrict__ wlo,
    const float* __restrict__ bias, float* __restrict__ xp) {
  __shared__ unsigned short Ah[128 * 32], Al[128 * 32], Bh[128 * 32], Bl[128 * 32];
  const int tid = threadIdx.x, lane = tid & 63, wv = tid >> 6;
  const int l15 = lane & 15, kg = lane >> 4;
  const int wm = wv >> 1, wn = wv & 1;
  const size_t aRow0 = (size_t)blockIdx.y * 128, bRow0 = (size_t)blockIdx.x * 128;

  f32x4 acc[4][4];
#pragma unroll
  for (int a = 0; a < 4; ++a)
#pragma unroll
    for (int b2 = 0; b2 < 4; ++b2)
#pragma unroll
      for (int e = 0; e < 4; ++e) acc[a][b2][e] = 0.f;

  const int r0 = wv * 2;
  const int rowIn = lane >> 2;
  const int kb = (lane & 3) * 16;

  for (int kt = 0; kt < 32; ++kt) {
#pragma unroll
    for (int j = 0; j < 2; ++j) {
      const int ld = (r0 + j) * 1024;
      const int row = (r0 + j) * 16 + rowIn;
      const size_t ka = (size_t)kt * 64 + kb;
      gld16((const char*)xhi + (aRow0 + row) * 2048 + ka, (char*)Ah + ld);
      gld16((const char*)xlo + (aRow0 + row) * 2048 + ka, (char*)Al + ld);
      gld16((const char*)whi + (bRow0 + row) * 2048 + ka, (char*)Bh + ld);
      gld16((const char*)wlo + (bRow0 + row) * 2048 + ka, (char*)Bl + ld);
    }
    __syncthreads();
    bf16x8 ah[4], al[4], bh[4], bl[4];
#pragma unroll
    for (int f = 0; f < 4; ++f) {
      ah[f] = *(const bf16x8*)&Ah[(wm * 64 + f * 16 + l15) * 32 + kg * 8];
      al[f] = *(const bf16x8*)&Al[(wm * 64 + f * 16 + l15) * 32 + kg * 8];
      bh[f] = *(const bf16x8*)&Bh[(wn * 64 + f * 16 + l15) * 32 + kg * 8];
      bl[f] = *(const bf16x8*)&Bl[(wn * 64 + f * 16 + l15) * 32 + kg * 8];
    }
#pragma unroll
    for (int mf = 0; mf < 4; ++mf)
#pragma unroll
      for (int nf = 0; nf < 4; ++nf) {
        acc[mf][nf] = mfma16(ah[mf], bh[nf], acc[mf][nf]);
        acc[mf][nf] = mfma16(al[mf], bh[nf], acc[mf][nf]);
        acc[mf][nf] = mfma16(ah[mf], bl[nf], acc[mf][nf]);
      }
    __syncthreads();
  }
#pragma unroll
  for (int nf = 0; nf < 4; ++nf) {
    const int col = (int)bRow0 + wn * 64 + nf * 16 + l15;
    const float bv = bias[col];
#pragma unroll
    for (int mf = 0; mf < 4; ++mf)
#pragma unroll
      for (int i = 0; i < 4; ++i) {
        const size_t m = aRow0 + (size_t)(wm * 64 + mf * 16 + kg * 4 + i);
        xp[m * G_ + col] = acc[mf][nf][i] + bv;
      }
  }
}

// ---------------- persistent recurrence ----------------
// 64 blocks x 1024 thr (16 waves = 4 gates x 4 K-sub-slices). Block nt owns H-cols
// nt*16..+16. h staged per K-quarter (256) into LDS via bulk coherent loads,
// double-buffered; MFMA A-frags via swizzled ds_read_b128. c register-resident.
__global__ __launch_bounds__(1024) void lstm_persist(
    const float* __restrict__ xp_c,
    unsigned short* __restrict__ h_hi0, unsigned short* __restrict__ h_lo0,
    unsigned short* __restrict__ h_hi1, unsigned short* __restrict__ h_lo1,
    float* __restrict__ c,
    const unsigned short* __restrict__ whi, const unsigned short* __restrict__ wlo,
    float* __restrict__ out, unsigned* __restrict__ cnt, int t0, int Tc) {
  // LDS: two 64KB h-quarter buffers (hi 32K + lo 32K each); gl reduce overlays buf0.
  __shared__ __align__(16) char ldsb[131072];
  const int tid = threadIdx.x, lane = tid & 63, wv = tid >> 6;
  const int g = wv & 3, kh = wv >> 2;
  const int l15 = lane & 15, kg = lane >> 4;
  const int nt = blockIdx.x;

  // w_hh B-frags: hi plane register-resident; lo plane streamed (L2-stable).
  const int wrow = g * 1024 + nt * 16 + l15;
  const unsigned short* bp_h = whi + (size_t)wrow * H_ + kg * 8;
  const unsigned short* bp_l = wlo + (size_t)wrow * H_ + kg * 8;
  bf16x8 bh_r[8];  // [q*2+kt] -> K = q*256 + kh*64 + kt*32
#pragma unroll
  for (int j = 0; j < 8; ++j)
    bh_r[j] = *(const bf16x8*)(bp_h + (j >> 1) * 256 + kh * 64 + (j & 1) * 32);

  const int eb = tid >> 4, ej = tid & 15;
  const int col = nt * 16 + ej;
  const int ci = eb * H_ + col;
  float creg = c[ci];

  // per-thread stage identity: unit u = tid + k*1024 -> row r=u>>6, 8B-col e=u&63
  // LDS slot: chunk c2=e>>1 (16B), half=e&1; byte = r*512 + ((c2^(r&7))<<4) + half*8
  int soff[4], goff[4];
#pragma unroll
  for (int k = 0; k < 4; ++k) {
    const int u = tid + k * 1024, r = u >> 6, e = u & 63;
    goff[k] = r * 2048 + e * 8;                                  // + q*512 at use
    soff[k] = r * 512 + (((e >> 1) ^ (r & 7)) << 4) + (e & 1) * 8;
  }
  // A-frag read offsets (row = mf*16+l15, chunk = kh*8+kt*4+kg)
  int aoff[4][2];
#pragma unroll
  for (int mf = 0; mf < 4; ++mf)
#pragma unroll
    for (int kt = 0; kt < 2; ++kt) {
      const int row = mf * 16 + l15, c2 = kh * 8 + kt * 4 + kg;
      aoff[mf][kt] = row * 512 + ((c2 ^ (row & 7)) << 4);
    }

  for (int tl = 0; tl < Tc; ++tl) {
    const int t = t0 + tl;
    const char* hi_in = (const char*)((t & 1) ? h_hi1 : h_hi0);
    const char* lo_in = (const char*)((t & 1) ? h_lo1 : h_lo0);
    unsigned short* hi_out = (t & 1) ? h_hi0 : h_hi1;
    unsigned short* lo_out = (t & 1) ? h_lo0 : h_lo1;

    // xp loads issued early (cached; xp precomputed before this kernel)
    const float* xpr = xp_c + ((size_t)tl * B_ + eb) * G_;
    float xq0 = xpr[col], xq1 = xpr[col + 1024], xq2 = xpr[col + 2048], xq3 = xpr[col + 3072];

    f32x4 acc[4];
#pragma unroll
    for (int m = 0; m < 4; ++m)
#pragma unroll
      for (int e = 0; e < 4; ++e) acc[m][e] = 0.f;

    // ---- prologue: stage quarter 0 into buf0 ----
    {
      u64 sh[4], sl[4];
#pragma unroll
      for (int k = 0; k < 4; ++k) {
        sh[k] = ldc8(hi_in + goff[k]);
        sl[k] = ldc8(lo_in + goff[k]);
      }
#pragma unroll
      for (int k = 0; k < 4; ++k) {
        *(u64*)(ldsb + soff[k]) = sh[k];
        *(u64*)(ldsb + 32768 + soff[k]) = sl[k];
      }
      __syncthreads();
    }

    // ---- 4 quarters, double-buffered ----
#pragma unroll
    for (int q = 0; q < 4; ++q) {
      const int bufA = (q & 1) * 65536, bufB = ((q + 1) & 1) * 65536;
      u64 sh[4], sl[4];
      if (q < 3) {  // issue next-quarter coherent loads early (fly under MFMA)
        const int gq = (q + 1) * 512;
#pragma unroll
        for (int k = 0; k < 4; ++k) {
          sh[k] = ldc8(hi_in + gq + goff[k]);
          sl[k] = ldc8(lo_in + gq + goff[k]);
        }
        asm volatile("" : "+v"(sh[0]), "+v"(sh[1]), "+v"(sh[2]), "+v"(sh[3]),
                          "+v"(sl[0]), "+v"(sl[1]), "+v"(sl[2]), "+v"(sl[3]));
      }
#pragma unroll
      for (int kt = 0; kt < 2; ++kt) {
        const bf16x8 bh = bh_r[q * 2 + kt];
        const bf16x8 bl = *(const bf16x8*)(bp_l + q * 256 + kh * 64 + kt * 32);
#pragma unroll
        for (int mf = 0; mf < 4; ++mf) {
          const bf16x8 ah = *(const bf16x8*)(ldsb + bufA + aoff[mf][kt]);
          const bf16x8 al = *(const bf16x8*)(ldsb + bufA + 32768 + aoff[mf][kt]);
          acc[mf] = mfma16(ah, bh, acc[mf]);
          acc[mf] = mfma16(al, bh, acc[mf]);
          acc[mf] = mfma16(ah, bl, acc[mf]);
        }
      }
      if (q < 3) {
#pragma unroll
        for (int k = 0; k < 4; ++k) {
          *(u64*)(ldsb + bufB + soff[k]) = sh[k];
          *(u64*)(ldsb + bufB + 32768 + soff[k]) = sl[k];
        }
        __syncthreads();
      }
    }

    // ---- cross-wave reduce (gl overlays buf0; q=3 used buf1, q2 reads sync-protected)
    float* gl = (float*)ldsb;  // [16][64][16]
#pragma unroll
    for (int mf = 0; mf < 4; ++mf)
#pragma unroll
      for (int i = 0; i < 4; ++i)
        gl[(wv * 64 + mf * 16 + kg * 4 + i) * 16 + l15] = acc[mf][i];
    __syncthreads();

    float xs[4];
#pragma unroll
    for (int gg = 0; gg < 4; ++gg) {
      float s = 0.f;
#pragma unroll
      for (int k2 = 0; k2 < 4; ++k2) s += gl[((k2 * 4 + gg) * 64 + eb) * 16 + ej];
      xs[gg] = s;
    }
    const float xi = xs[0] + xq0;
    const float xf = xs[1] + xq1;
    const float xg = xs[2] + xq2;
    const float xo = xs[3] + xq3;
    const float ig = 1.f / (1.f + __expf(-xi));
    const float fg = 1.f / (1.f + __expf(-xf));
    const float gt = tanhf(xg);
    const float og = 1.f / (1.f + __expf(-xo));
    creg = fg * creg + ig * gt;
    const float hn = og * tanhf(creg);
    const unsigned short hh = f2bf(hn);
    const unsigned short hl = f2bf(hn - bf2f(hh));
    __hip_atomic_store(hi_out + ci, hh, __ATOMIC_RELAXED, __HIP_MEMORY_SCOPE_AGENT);
    __hip_atomic_store(lo_out + ci, hl, __ATOMIC_RELAXED, __HIP_MEMORY_SCOPE_AGENT);
    if (t == S_ - 1) out[ci] = creg;

    // ---- grid barrier: release arrival, BOUNDED relaxed spin (container safety),
    //      no cache-wide invalidate ----
    __syncthreads();  // all publishes drained (vmcnt 0 per wave) before arrival
    if (tid == 0) {
      __hip_atomic_fetch_add(cnt, 1u, __ATOMIC_RELEASE, __HIP_MEMORY_SCOPE_AGENT);
      const unsigned tgt = (unsigned)(t + 1) * (unsigned)NBLK;
      // bounded spin: ~4M polls (~0.3 s) then give up -> wrong results, not a hang
      unsigned guard = 0u;
      while (__hip_atomic_load(cnt, __ATOMIC_RELAXED, __HIP_MEMORY_SCOPE_AGENT) < tgt &&
             ++guard < (1u << 22)) {
      }
      __atomic_signal_fence(__ATOMIC_ACQUIRE);
    }
    __syncthreads();
  }
  c[ci] = creg;
}

extern "C" void kernel_launch(void* const* d_in, const int* in_sizes, int n_in,
                              void* d_out, int out_size, void* d_ws, size_t ws_size,
                              hipStream_t stream) {
  const float* x = (const float*)d_in[0];
  const float* h0 = (const float*)d_in[1];
  const float* c0 = (const float*)d_in[2];
  const float* w_ih = (const float*)d_in[3];
  const float* w_hh = (const float*)d_in[4];
  const float* b_ih = (const float*)d_in[5];
  const float* b_hh = (const float*)d_in[6];
  float* out = (float*)d_out;

  char* p = (char*)d_ws;
  auto carve = [&](size_t bytes) {
    char* r = p;
    p += (bytes + 255) & ~(size_t)255;
    return r;
  };
  const size_t wBytes = (size_t)G_ * H_ * 2;  // 8 MB per plane
  unsigned short* wih_hi = (unsigned short*)carve(wBytes);
  unsigned short* wih_lo = (unsigned short*)carve(wBytes);
  unsigned short* whh_hi = (unsigned short*)carve(wBytes);
  unsigned short* whh_lo = (unsigned short*)carve(wBytes);
  float* bias = (float*)carve((size_t)G_ * 4);
  unsigned short* hhi0 = (unsigned short*)carve((size_t)B_ * H_ * 2);
  unsigned short* hhi1 = (unsigned short*)carve((size_t)B_ * H_ * 2);
  unsigned short* hlo0 = (unsigned short*)carve((size_t)B_ * H_ * 2);
  unsigned short* hlo1 = (unsigned short*)carve((size_t)B_ * H_ * 2);
  float* cbuf = (float*)carve((size_t)B_ * H_ * 4);
  unsigned* cnt = (unsigned*)carve(256);
  const size_t fixed = (size_t)(p - (char*)d_ws);

  const size_t per_t = (size_t)B_ * I_ * 2 * 2 + (size_t)B_ * G_ * 4 + 1024;
  long long Tl = 2;
  if (ws_size > fixed) Tl = (long long)((ws_size - fixed) / per_t);
  int T = (int)(Tl > S_ ? S_ : Tl);
  T &= ~1;
  if (T < 2) T = 2;
  unsigned short* xhi = (unsigned short*)carve((size_t)T * B_ * I_ * 2);
  unsigned short* xlo = (unsigned short*)carve((size_t)T * B_ * I_ * 2);
  float* xp = (float*)carve((size_t)T * B_ * G_ * 4);

  split_mat<<<(G_ * H_ / 4 + 255) / 256, 256, 0, stream>>>(w_ih, wih_hi, wih_lo, G_ * H_ / 4);
  split_mat<<<(G_ * H_ / 4 + 255) / 256, 256, 0, stream>>>(w_hh, whh_hi, whh_lo, G_ * H_ / 4);
  prep<<<(B_ * H_ + 255) / 256, 256, 0, stream>>>(h0, c0, b_ih, b_hh, hhi0, hlo0, cbuf, bias,
                                                  cnt);

  int t0 = 0;
  while (t0 < S_) {
    const int Tc = (S_ - t0 < T) ? (S_ - t0) : T;
    split_x<<<Tc * B_ * I_ / 4 / 256, 256, 0, stream>>>(x, xhi, xlo, t0);
    xproj_gemm<<<dim3(G_ / 128, Tc * B_ / 128), 256, 0, stream>>>(xhi, xlo, wih_hi, wih_lo,
                                                                  bias, xp);
    lstm_persist<<<NBLK, 1024, 0, stream>>>(xp, hhi0, hlo0, hhi1, hlo1, cbuf, whh_hi, whh_lo,
                                            out, cnt, t0, Tc);
    t0 += Tc;
  }
}